// Round 1
// baseline (66.525 us; speedup 1.0000x reference)
//
#include <hip/hip_runtime.h>
#include <hip/hip_bf16.h>

// InferenceLinear: out[m][n] = sum_k x[m][k] * (q[n][k]*qrange[n][k/256] + qmin[n][k/256])
// M=512 (8*64), N=2048, K=4096, 16 groups of 256.
// Strategy: fused dequant bf16 MFMA GEMM. BM=BN=BK=64, 256 threads (4 waves 2x2,
// each wave 32x32 out via 2x2 16x16x32 fragments). Grid 32x8 = 256 blocks = 1/CU.
// LDS tiles XOR-swizzled at 16B slots to avoid ds_read_b128 bank conflicts.

#define M_T 512
#define N_T 2048
#define K_T 4096
#define NGRP 16
#define BM 64
#define BN 64
#define BK 64
#define NT (K_T / BK)

typedef __attribute__((ext_vector_type(8))) short mfrag_t;           // 8 bf16 (4 VGPR)
typedef __attribute__((ext_vector_type(8))) unsigned short u16x8;
typedef __attribute__((ext_vector_type(4))) float f32x4;

__device__ __forceinline__ unsigned short f2bf(float f) {
  __hip_bfloat16 h = __float2bfloat16(f);
  union { __hip_bfloat16 h; unsigned short u; } c;
  c.h = h;
  return c.u;
}

__global__ __launch_bounds__(256, 1) void dq_gemm_kernel(
    const float* __restrict__ x, const int* __restrict__ qw,
    const float* __restrict__ qrange, const float* __restrict__ qmin,
    float* __restrict__ out) {
  // swizzled [row][slot^(row&7)] storage, 8-elem (16B) slots
  __shared__ __align__(16) unsigned short As[BM * BK];
  __shared__ __align__(16) unsigned short Bs[BN * BK];

  const int tid = threadIdx.x;
  const int n0 = blockIdx.x * BN;
  const int m0 = blockIdx.y * BM;

  // staging mapping: thread -> (row, 16-elem segment)
  const int srow = tid >> 2;   // 0..63
  const int sseg = tid & 3;    // 0..3

  const float* xp = x + (size_t)(m0 + srow) * K_T + sseg * 16;
  const int* qp = qw + (size_t)(n0 + srow) * K_T + sseg * 16;
  const float* qrp = qrange + (size_t)(n0 + srow) * NGRP;
  const float* qmp = qmin + (size_t)(n0 + srow) * NGRP;

  // compute mapping
  const int lane = tid & 63;
  const int wv = tid >> 6;
  const int wm = (wv >> 1) * 32;
  const int wn = (wv & 1) * 32;
  const int lr = lane & 15;    // row/col within fragment
  const int lq = lane >> 4;    // 0..3 -> k chunk

  float4 av[4];
  int4 qv[4];
  float sc, mn;

  // prologue loads (t=0)
  {
    const float* a = xp;
    av[0] = *(const float4*)(a + 0);
    av[1] = *(const float4*)(a + 4);
    av[2] = *(const float4*)(a + 8);
    av[3] = *(const float4*)(a + 12);
    const int4* q = (const int4*)qp;
    qv[0] = q[0]; qv[1] = q[1]; qv[2] = q[2]; qv[3] = q[3];
    sc = qrp[0];
    mn = qmp[0];
  }

  f32x4 acc[2][2] = {};

  const int rx7 = srow & 7;
  const int abase = srow * BK;
  const int wslot0 = ((sseg * 2) ^ rx7) << 3;
  const int wslot1 = ((sseg * 2 + 1) ^ rx7) << 3;
  const int rxl = lr & 7;  // read-side xor (row&7 == lr&7 since wm/wn,fm*16 are mult of 8)

  for (int t = 0; t < NT; ++t) {
    // ---- stage regs -> LDS (convert to bf16 / dequant) ----
    u16x8 pa0, pa1, pb0, pb1;
    pa0[0] = f2bf(av[0].x); pa0[1] = f2bf(av[0].y); pa0[2] = f2bf(av[0].z); pa0[3] = f2bf(av[0].w);
    pa0[4] = f2bf(av[1].x); pa0[5] = f2bf(av[1].y); pa0[6] = f2bf(av[1].z); pa0[7] = f2bf(av[1].w);
    pa1[0] = f2bf(av[2].x); pa1[1] = f2bf(av[2].y); pa1[2] = f2bf(av[2].z); pa1[3] = f2bf(av[2].w);
    pa1[4] = f2bf(av[3].x); pa1[5] = f2bf(av[3].y); pa1[6] = f2bf(av[3].z); pa1[7] = f2bf(av[3].w);
    pb0[0] = f2bf((float)qv[0].x * sc + mn); pb0[1] = f2bf((float)qv[0].y * sc + mn);
    pb0[2] = f2bf((float)qv[0].z * sc + mn); pb0[3] = f2bf((float)qv[0].w * sc + mn);
    pb0[4] = f2bf((float)qv[1].x * sc + mn); pb0[5] = f2bf((float)qv[1].y * sc + mn);
    pb0[6] = f2bf((float)qv[1].z * sc + mn); pb0[7] = f2bf((float)qv[1].w * sc + mn);
    pb1[0] = f2bf((float)qv[2].x * sc + mn); pb1[1] = f2bf((float)qv[2].y * sc + mn);
    pb1[2] = f2bf((float)qv[2].z * sc + mn); pb1[3] = f2bf((float)qv[2].w * sc + mn);
    pb1[4] = f2bf((float)qv[3].x * sc + mn); pb1[5] = f2bf((float)qv[3].y * sc + mn);
    pb1[6] = f2bf((float)qv[3].z * sc + mn); pb1[7] = f2bf((float)qv[3].w * sc + mn);

    *(u16x8*)&As[abase + wslot0] = pa0;
    *(u16x8*)&As[abase + wslot1] = pa1;
    *(u16x8*)&Bs[abase + wslot0] = pb0;
    *(u16x8*)&Bs[abase + wslot1] = pb1;
    __syncthreads();

    // ---- issue next tile's global loads (overlap with MFMA phase) ----
    if (t + 1 < NT) {
      const float* a = xp + (size_t)(t + 1) * BK;
      av[0] = *(const float4*)(a + 0);
      av[1] = *(const float4*)(a + 4);
      av[2] = *(const float4*)(a + 8);
      av[3] = *(const float4*)(a + 12);
      const int4* q = (const int4*)(qp + (size_t)(t + 1) * BK);
      qv[0] = q[0]; qv[1] = q[1]; qv[2] = q[2]; qv[3] = q[3];
      const int g = (t + 1) >> 2;  // BK=64, group=256 -> g constant per tile
      sc = qrp[g];
      mn = qmp[g];
    }

    // ---- compute: 2 K-substeps of 32, 2x2 fragments ----
#pragma unroll
    for (int kk = 0; kk < 2; ++kk) {
      const int so = ((kk * 4 + lq) ^ rxl) << 3;
      mfrag_t af0 = *(const mfrag_t*)&As[(wm + lr) * BK + so];
      mfrag_t af1 = *(const mfrag_t*)&As[(wm + 16 + lr) * BK + so];
      mfrag_t bf0 = *(const mfrag_t*)&Bs[(wn + lr) * BK + so];
      mfrag_t bf1 = *(const mfrag_t*)&Bs[(wn + 16 + lr) * BK + so];
      acc[0][0] = __builtin_amdgcn_mfma_f32_16x16x32_bf16(af0, bf0, acc[0][0], 0, 0, 0);
      acc[0][1] = __builtin_amdgcn_mfma_f32_16x16x32_bf16(af0, bf1, acc[0][1], 0, 0, 0);
      acc[1][0] = __builtin_amdgcn_mfma_f32_16x16x32_bf16(af1, bf0, acc[1][0], 0, 0, 0);
      acc[1][1] = __builtin_amdgcn_mfma_f32_16x16x32_bf16(af1, bf1, acc[1][1], 0, 0, 0);
    }
    __syncthreads();
  }

  // ---- epilogue: C/D layout col=lane&15, row=(lane>>4)*4+reg (measured m89/m91) ----
#pragma unroll
  for (int fm = 0; fm < 2; ++fm) {
#pragma unroll
    for (int fn = 0; fn < 2; ++fn) {
      const int r0 = m0 + wm + fm * 16 + lq * 4;
      const int c = n0 + wn + fn * 16 + lr;
      float* op = out + (size_t)r0 * N_T + c;
      op[0 * (size_t)N_T] = acc[fm][fn][0];
      op[1 * (size_t)N_T] = acc[fm][fn][1];
      op[2 * (size_t)N_T] = acc[fm][fn][2];
      op[3 * (size_t)N_T] = acc[fm][fn][3];
    }
  }
}

extern "C" void kernel_launch(void* const* d_in, const int* in_sizes, int n_in,
                              void* d_out, int out_size, void* d_ws, size_t ws_size,
                              hipStream_t stream) {
  const float* x = (const float*)d_in[0];
  const int* qw = (const int*)d_in[1];
  const float* qr = (const float*)d_in[2];
  const float* qm = (const float*)d_in[3];
  float* out = (float*)d_out;
  dim3 grid(N_T / BN, M_T / BM);
  dq_gemm_kernel<<<grid, dim3(256, 1, 1), 0, stream>>>(x, qw, qr, qm, out);
}

// Round 2
// 51.759 us; speedup vs baseline: 1.2853x; 1.2853x over previous
//
#include <hip/hip_runtime.h>
#include <hip/hip_bf16.h>

// InferenceLinear: out[m][n] = sum_k x[m][k] * (q[n][k]*qrange[n][k/256] + qmin[n][k/256])
// M=512, N=2048, K=4096, 16 groups of 256.
// R2: split-K=4 (grid 32x8x4 = 1024 blocks = 4/CU = 50% occupancy) + double-buffered
// LDS (1 barrier per K-tile) + fp32 atomicAdd epilogue into zeroed d_out.
// BM=BN=BK=64, 256 threads (4 waves 2x2, each wave 32x32 via 2x2 16x16x32 frags).

#define M_T 512
#define N_T 2048
#define K_T 4096
#define NGRP 16
#define BM 64
#define BN 64
#define BK 64
#define KSPLIT 4
#define KC (K_T / KSPLIT)   // 1024 per block
#define NTC (KC / BK)       // 16 tiles

typedef __attribute__((ext_vector_type(8))) short mfrag_t;           // 8 bf16 (4 VGPR)
typedef __attribute__((ext_vector_type(8))) unsigned short u16x8;
typedef __attribute__((ext_vector_type(4))) float f32x4;

__device__ __forceinline__ unsigned short f2bf(float f) {
  union { __hip_bfloat16 h; unsigned short u; } c;
  c.h = __float2bfloat16(f);
  return c.u;
}

__global__ __launch_bounds__(256, 4) void dq_gemm_kernel(
    const float* __restrict__ x, const int* __restrict__ qw,
    const float* __restrict__ qrange, const float* __restrict__ qmin,
    float* __restrict__ out) {
  // double-buffered, swizzled [row][slot^(row&7)] storage, 8-elem (16B) slots
  __shared__ __align__(16) unsigned short As[2][BM * BK];
  __shared__ __align__(16) unsigned short Bs[2][BM * BK];

  const int tid = threadIdx.x;
  const int n0 = blockIdx.x * BN;
  const int m0 = blockIdx.y * BM;
  const int kc = blockIdx.z;        // k-chunk index
  const int kbase = kc * KC;

  // staging mapping: thread -> (row, 16-elem segment)
  const int srow = tid >> 2;   // 0..63
  const int sseg = tid & 3;    // 0..3

  const float* xp = x + (size_t)(m0 + srow) * K_T + kbase + sseg * 16;
  const int* qp = qw + (size_t)(n0 + srow) * K_T + kbase + sseg * 16;
  const float* qrp = qrange + (size_t)(n0 + srow) * NGRP;
  const float* qmp = qmin + (size_t)(n0 + srow) * NGRP;

  // compute mapping
  const int lane = tid & 63;
  const int wv = tid >> 6;
  const int wm = (wv >> 1) * 32;
  const int wn = (wv & 1) * 32;
  const int lr = lane & 15;    // row/col within fragment
  const int lq = lane >> 4;    // 0..3 -> k chunk

  float4 av[4];
  int4 qv[4];
  float sc, mn;

  // prologue loads (t=0)
  {
    const float* a = xp;
    av[0] = *(const float4*)(a + 0);
    av[1] = *(const float4*)(a + 4);
    av[2] = *(const float4*)(a + 8);
    av[3] = *(const float4*)(a + 12);
    const int4* q = (const int4*)qp;
    qv[0] = q[0]; qv[1] = q[1]; qv[2] = q[2]; qv[3] = q[3];
    sc = qrp[kc * 4];
    mn = qmp[kc * 4];
  }

  f32x4 acc[2][2] = {};

  const int rx7 = srow & 7;
  const int abase = srow * BK;
  const int wslot0 = ((sseg * 2) ^ rx7) << 3;
  const int wslot1 = ((sseg * 2 + 1) ^ rx7) << 3;
  const int rxl = lr & 7;  // read-side xor

  // stage t=0 into buffer 0
  {
    u16x8 pa0, pa1, pb0, pb1;
    pa0[0] = f2bf(av[0].x); pa0[1] = f2bf(av[0].y); pa0[2] = f2bf(av[0].z); pa0[3] = f2bf(av[0].w);
    pa0[4] = f2bf(av[1].x); pa0[5] = f2bf(av[1].y); pa0[6] = f2bf(av[1].z); pa0[7] = f2bf(av[1].w);
    pa1[0] = f2bf(av[2].x); pa1[1] = f2bf(av[2].y); pa1[2] = f2bf(av[2].z); pa1[3] = f2bf(av[2].w);
    pa1[4] = f2bf(av[3].x); pa1[5] = f2bf(av[3].y); pa1[6] = f2bf(av[3].z); pa1[7] = f2bf(av[3].w);
    pb0[0] = f2bf((float)qv[0].x * sc + mn); pb0[1] = f2bf((float)qv[0].y * sc + mn);
    pb0[2] = f2bf((float)qv[0].z * sc + mn); pb0[3] = f2bf((float)qv[0].w * sc + mn);
    pb0[4] = f2bf((float)qv[1].x * sc + mn); pb0[5] = f2bf((float)qv[1].y * sc + mn);
    pb0[6] = f2bf((float)qv[1].z * sc + mn); pb0[7] = f2bf((float)qv[1].w * sc + mn);
    pb1[0] = f2bf((float)qv[2].x * sc + mn); pb1[1] = f2bf((float)qv[2].y * sc + mn);
    pb1[2] = f2bf((float)qv[2].z * sc + mn); pb1[3] = f2bf((float)qv[2].w * sc + mn);
    pb1[4] = f2bf((float)qv[3].x * sc + mn); pb1[5] = f2bf((float)qv[3].y * sc + mn);
    pb1[6] = f2bf((float)qv[3].z * sc + mn); pb1[7] = f2bf((float)qv[3].w * sc + mn);
    *(u16x8*)&As[0][abase + wslot0] = pa0;
    *(u16x8*)&As[0][abase + wslot1] = pa1;
    *(u16x8*)&Bs[0][abase + wslot0] = pb0;
    *(u16x8*)&Bs[0][abase + wslot1] = pb1;
  }
  __syncthreads();

  for (int t = 0; t < NTC; ++t) {
    const int cur = t & 1;
    // ---- issue next tile's global loads early (hide under MFMA phase) ----
    const bool more = (t + 1 < NTC);
    if (more) {
      const float* a = xp + (size_t)(t + 1) * BK;
      av[0] = *(const float4*)(a + 0);
      av[1] = *(const float4*)(a + 4);
      av[2] = *(const float4*)(a + 8);
      av[3] = *(const float4*)(a + 12);
      const int4* q = (const int4*)(qp + (size_t)(t + 1) * BK);
      qv[0] = q[0]; qv[1] = q[1]; qv[2] = q[2]; qv[3] = q[3];
      const int g = kc * 4 + ((t + 1) >> 2);  // group of 256 = 4 tiles of 64
      sc = qrp[g];
      mn = qmp[g];
    }

    // ---- compute tile t from buf[cur]: 2 K-substeps of 32, 2x2 fragments ----
#pragma unroll
    for (int kk = 0; kk < 2; ++kk) {
      const int so = ((kk * 4 + lq) ^ rxl) << 3;
      mfrag_t af0 = *(const mfrag_t*)&As[cur][(wm + lr) * BK + so];
      mfrag_t af1 = *(const mfrag_t*)&As[cur][(wm + 16 + lr) * BK + so];
      mfrag_t bf0 = *(const mfrag_t*)&Bs[cur][(wn + lr) * BK + so];
      mfrag_t bf1 = *(const mfrag_t*)&Bs[cur][(wn + 16 + lr) * BK + so];
      acc[0][0] = __builtin_amdgcn_mfma_f32_16x16x32_bf16(af0, bf0, acc[0][0], 0, 0, 0);
      acc[0][1] = __builtin_amdgcn_mfma_f32_16x16x32_bf16(af0, bf1, acc[0][1], 0, 0, 0);
      acc[1][0] = __builtin_amdgcn_mfma_f32_16x16x32_bf16(af1, bf0, acc[1][0], 0, 0, 0);
      acc[1][1] = __builtin_amdgcn_mfma_f32_16x16x32_bf16(af1, bf1, acc[1][1], 0, 0, 0);
    }

    // ---- stage t+1 into buf[cur^1]; single barrier per tile ----
    if (more) {
      u16x8 pa0, pa1, pb0, pb1;
      pa0[0] = f2bf(av[0].x); pa0[1] = f2bf(av[0].y); pa0[2] = f2bf(av[0].z); pa0[3] = f2bf(av[0].w);
      pa0[4] = f2bf(av[1].x); pa0[5] = f2bf(av[1].y); pa0[6] = f2bf(av[1].z); pa0[7] = f2bf(av[1].w);
      pa1[0] = f2bf(av[2].x); pa1[1] = f2bf(av[2].y); pa1[2] = f2bf(av[2].z); pa1[3] = f2bf(av[2].w);
      pa1[4] = f2bf(av[3].x); pa1[5] = f2bf(av[3].y); pa1[6] = f2bf(av[3].z); pa1[7] = f2bf(av[3].w);
      pb0[0] = f2bf((float)qv[0].x * sc + mn); pb0[1] = f2bf((float)qv[0].y * sc + mn);
      pb0[2] = f2bf((float)qv[0].z * sc + mn); pb0[3] = f2bf((float)qv[0].w * sc + mn);
      pb0[4] = f2bf((float)qv[1].x * sc + mn); pb0[5] = f2bf((float)qv[1].y * sc + mn);
      pb0[6] = f2bf((float)qv[1].z * sc + mn); pb0[7] = f2bf((float)qv[1].w * sc + mn);
      pb1[0] = f2bf((float)qv[2].x * sc + mn); pb1[1] = f2bf((float)qv[2].y * sc + mn);
      pb1[2] = f2bf((float)qv[2].z * sc + mn); pb1[3] = f2bf((float)qv[2].w * sc + mn);
      pb1[4] = f2bf((float)qv[3].x * sc + mn); pb1[5] = f2bf((float)qv[3].y * sc + mn);
      pb1[6] = f2bf((float)qv[3].z * sc + mn); pb1[7] = f2bf((float)qv[3].w * sc + mn);
      const int nxt = cur ^ 1;
      *(u16x8*)&As[nxt][abase + wslot0] = pa0;
      *(u16x8*)&As[nxt][abase + wslot1] = pa1;
      *(u16x8*)&Bs[nxt][abase + wslot0] = pb0;
      *(u16x8*)&Bs[nxt][abase + wslot1] = pb1;
      __syncthreads();
    }
  }

  // ---- epilogue: atomicAdd partials. C/D layout col=lane&15, row=(lane>>4)*4+reg ----
#pragma unroll
  for (int fm = 0; fm < 2; ++fm) {
#pragma unroll
    for (int fn = 0; fn < 2; ++fn) {
      const int r0 = m0 + wm + fm * 16 + lq * 4;
      const int c = n0 + wn + fn * 16 + lr;
      float* op = out + (size_t)r0 * N_T + c;
      atomicAdd(&op[0 * (size_t)N_T], acc[fm][fn][0]);
      atomicAdd(&op[1 * (size_t)N_T], acc[fm][fn][1]);
      atomicAdd(&op[2 * (size_t)N_T], acc[fm][fn][2]);
      atomicAdd(&op[3 * (size_t)N_T], acc[fm][fn][3]);
    }
  }
}

extern "C" void kernel_launch(void* const* d_in, const int* in_sizes, int n_in,
                              void* d_out, int out_size, void* d_ws, size_t ws_size,
                              hipStream_t stream) {
  const float* x = (const float*)d_in[0];
  const int* qw = (const int*)d_in[1];
  const float* qr = (const float*)d_in[2];
  const float* qm = (const float*)d_in[3];
  float* out = (float*)d_out;
  hipMemsetAsync(out, 0, (size_t)M_T * N_T * sizeof(float), stream);
  dim3 grid(N_T / BN, M_T / BM, KSPLIT);
  dq_gemm_kernel<<<grid, dim3(256, 1, 1), 0, stream>>>(x, qw, qr, qm, out);
}